// Round 10
// baseline (59.745 us; speedup 1.0000x reference)
//
#include <hip/hip_runtime.h>
#include <hip/hip_bf16.h>

#define NCLS 13
#define ROWS 16                          // rows per tile
#define BLOCK 256                        // 4 waves; wave w owns rows 4w..4w+3
#define TPB 16                           // tiles per block
#define NBUF 4                           // quad buffer, 3-deep prefetch
#define C_FLOATS (ROWS * NCLS * NCLS)    // 2704 floats (10816 B)
#define XS_FLOATS (ROWS * NCLS)          // 208 floats
#define CW 676                           // C floats per wave (4 rows * 169)
#define CW4 169                          // C float4s per wave

// async global->LDS DMA, 16B/lane; HW writes LDS at uniform base + lane*16
__device__ __forceinline__ void async_cp16(const float* g, float* l) {
    __builtin_amdgcn_global_load_lds(
        (__attribute__((address_space(1))) void*)(const_cast<float*>(g)),
        (__attribute__((address_space(3))) void*)(l),
        16, 0, 0);
}

__global__ __launch_bounds__(BLOCK) void rnorm_kernel(
    const float* __restrict__ input,
    const int* __restrict__ target,
    const float* __restrict__ s,
    const float* __restrict__ C,
    float* __restrict__ out,
    int ntiles)
{
    // 4 * (10816 + 832 + 832 + 64) = 50176 B -> 3 blocks/CU
    __shared__ __align__(16) float cb[NBUF][C_FLOATS];
    __shared__ __align__(16) float xb[NBUF][XS_FLOATS];
    __shared__ __align__(16) float sb[NBUF][XS_FLOATS];
    __shared__ __align__(16) int   tb[NBUF][ROWS];
    __shared__ float wsum[4];

    const int tid  = threadIdx.x;
    const int w    = tid >> 6;    // wave 0..3
    const int lane = tid & 63;
    const int row  = tid >> 4;    // 0..15
    const int q    = tid & 15;    // 16 lanes per row, 13 active

    const int tile0 = blockIdx.x * TPB;
    const int nt = min(TPB, ntiles - tile0);
    float res_acc = 0.0f;

    // Exactly 4 global_load_lds per wave per stage (per-wave vmcnt accounting).
    // All C addressing in float4 units.
    auto stage = [&](int t_idx, int buf) {
        const int tile = tile0 + t_idx;
        const float4* Cg = (const float4*)(C + (size_t)tile * C_FLOATS) + w * CW4;
        float* cd = &cb[buf][w * CW];
        async_cp16((const float*)(Cg + lane),       cd + (size_t)lane * 4);
        async_cp16((const float*)(Cg + 64 + lane),  cd + (size_t)(64 + lane) * 4);
        if (lane < CW4 - 128)
            async_cp16((const float*)(Cg + 128 + lane), cd + (size_t)(128 + lane) * 4);
        if (w == 0) {
            const float4* xg = (const float4*)(input + (size_t)tile * XS_FLOATS);
            if (lane < XS_FLOATS / 4)
                async_cp16((const float*)(xg + lane), &xb[buf][0] + (size_t)lane * 4);
        } else if (w == 1) {
            const float4* sg = (const float4*)(s + (size_t)tile * XS_FLOATS);
            if (lane < XS_FLOATS / 4)
                async_cp16((const float*)(sg + lane), &sb[buf][0] + (size_t)lane * 4);
        } else {  // waves 2 and 3 both stage targets (identical data, benign)
            if (lane < ROWS / 4)
                async_cp16((const float*)(target + (size_t)tile * ROWS) + (size_t)lane * 4,
                           (float*)&tb[buf][0] + (size_t)lane * 4);
        }
    };

    if (nt > 0) {
        // prologue: 3-deep prefetch
        stage(0, 0);
        if (nt > 1) stage(1, 1);
        if (nt > 2) stage(2, 2);
        if (nt > 2)      asm volatile("s_waitcnt vmcnt(8)" ::: "memory");
        else if (nt > 1) asm volatile("s_waitcnt vmcnt(4)" ::: "memory");
        else             asm volatile("s_waitcnt vmcnt(0)" ::: "memory");
        __builtin_amdgcn_sched_barrier(0);
        __builtin_amdgcn_s_barrier();

        int bcur = 0;
        for (int t = 0; t < nt; ++t) {
            // issue tile t+3 (two stages stay in flight across the barrier)
            if (t + 3 < nt) {
                int bpre = bcur + 3; if (bpre >= NBUF) bpre -= NBUF;
                stage(t + 3, bpre);
            }

            // ---- compute tile t from LDS ----
            const float* cbt = cb[bcur];
            const float* xbt = xb[bcur];
            const float* sbt = sb[bcur];
            const int tt = tb[bcur][row];

            float sp = 0.0f, sy = 0.0f, dd = 0.0f;
            if (q < NCLS) {
                const float* crow = cbt + row * (NCLS * NCLS) + q * NCLS;
                const float* xrow = xbt + row * NCLS;
                float zye = 0.0f;
#pragma unroll
                for (int j = 0; j < NCLS; ++j)
                    zye = fmaf(crow[j], xrow[j], zye);
                const float zpe = crow[tt];            // one-hot column
                const float svi = sbt[row * NCLS + q];
                const float zp = svi - zpe, zy = svi - zye;
                sp = zp * zp; sy = zy * zy; dd = zy * zp;
            }

            sp += __shfl_xor(sp, 1); sp += __shfl_xor(sp, 2);
            sp += __shfl_xor(sp, 4); sp += __shfl_xor(sp, 8);
            sy += __shfl_xor(sy, 1); sy += __shfl_xor(sy, 2);
            sy += __shfl_xor(sy, 4); sy += __shfl_xor(sy, 8);
            dd += __shfl_xor(dd, 1); dd += __shfl_xor(dd, 2);
            dd += __shfl_xor(dd, 4); dd += __shfl_xor(dd, 8);

            if (q == 0)
                res_acc += sqrtf(sp) - dd / sqrtf(sy);

            if (t + 1 < nt) {
                // counted wait: tile t+1 landed; t+2/t+3 stay in flight
                if (t + 3 < nt)      asm volatile("s_waitcnt vmcnt(8)" ::: "memory");
                else if (t + 2 < nt) asm volatile("s_waitcnt vmcnt(4)" ::: "memory");
                else                 asm volatile("s_waitcnt vmcnt(0)" ::: "memory");
                __builtin_amdgcn_sched_barrier(0);
                __builtin_amdgcn_s_barrier();   // raw barrier: no implicit drain
            }
            bcur = (bcur + 1 == NBUF) ? 0 : bcur + 1;
        }
    }

    // ---- block reduction ----
#pragma unroll
    for (int off = 32; off > 0; off >>= 1)
        res_acc += __shfl_down(res_acc, off, 64);

    if (lane == 0) wsum[w] = res_acc;
    __syncthreads();
    if (tid == 0)
        atomicAdd(out, wsum[0] + wsum[1] + wsum[2] + wsum[3]);
}

extern "C" void kernel_launch(void* const* d_in, const int* in_sizes, int n_in,
                              void* d_out, int out_size, void* d_ws, size_t ws_size,
                              hipStream_t stream) {
    const float* input  = (const float*)d_in[0];
    const int*   target = (const int*)d_in[1];   // harness passes integers as int32
    const float* s      = (const float*)d_in[2];
    const float* C      = (const float*)d_in[3];
    // d_in[4] (instance_weights) is unused by the reference.

    float* out = (float*)d_out;
    int N = in_sizes[1];

    // harness poisons d_out and does not re-zero between replays
    hipMemsetAsync(out, 0, sizeof(float) * out_size, stream);

    const int ntiles = N / ROWS;                 // 16384
    const int grid = (ntiles + TPB - 1) / TPB;   // 1024
    rnorm_kernel<<<grid, BLOCK, 0, stream>>>(input, target, s, C, out, ntiles);
}

// Round 11
// 53.778 us; speedup vs baseline: 1.1110x; 1.1110x over previous
//
#include <hip/hip_runtime.h>
#include <hip/hip_bf16.h>

#define NCLS 13
#define BLOCK 256
#define GPB (BLOCK / 16)   // 16 row-groups per block, one row per 16-lane group

// align-4 float4: C/x rows are only 4B-aligned (13-float stride)
typedef float f4 __attribute__((ext_vector_type(4), aligned(4)));

__global__ __launch_bounds__(BLOCK) void rnorm_kernel(
    const float* __restrict__ input,
    const int* __restrict__ target,
    const float* __restrict__ s,
    const float* __restrict__ C,
    float* __restrict__ out,
    int N)
{
    __shared__ float wsum[4];
    const int tid = threadIdx.x;
    const int q   = tid & 15;   // lane within row-group; q<13 active
    const int g   = tid >> 4;   // row-group within block

    float res_acc = 0.0f;

    for (int row = blockIdx.x * GPB + g; row < N; row += gridDim.x * GPB) {
        float sp = 0.0f, sy = 0.0f, dd = 0.0f;
        if (q < NCLS) {
            // lane q owns output element i=q: reads C[row, q, :] directly
            const float* cr = C + (size_t)row * (NCLS * NCLS) + q * NCLS;
            const f4 c0 = *(const f4*)(cr);
            const f4 c1 = *(const f4*)(cr + 4);
            const f4 c2 = *(const f4*)(cr + 8);
            const float c12 = cr[12];

            const float* xr = input + (size_t)row * NCLS;
            const f4 x0 = *(const f4*)(xr);        // same lines for all 16 lanes: L1 broadcast
            const f4 x1 = *(const f4*)(xr + 4);
            const f4 x2 = *(const f4*)(xr + 8);
            const float x12 = xr[12];

            const int t = target[row];

            float zye = c12 * x12;
#pragma unroll
            for (int k = 0; k < 4; ++k) {
                zye = fmaf(c0[k], x0[k], zye);
                zye = fmaf(c1[k], x1[k], zye);
                zye = fmaf(c2[k], x2[k], zye);
            }
            // zpe = C[row, q, t] — compile-time-unrolled select, no runtime reg-indexing
            float zpe = c12;
#pragma unroll
            for (int k = 0; k < 4; ++k) {
                zpe = (t == k)     ? c0[k] : zpe;
                zpe = (t == k + 4) ? c1[k] : zpe;
                zpe = (t == k + 8) ? c2[k] : zpe;
            }

            const float svi = s[(size_t)row * NCLS + q];
            const float zp = svi - zpe, zy = svi - zye;
            sp = zp * zp; sy = zy * zy; dd = zy * zp;
        }

        // reduce over the 16-lane row group (inactive lanes contribute 0)
        sp += __shfl_xor(sp, 1); sp += __shfl_xor(sp, 2);
        sp += __shfl_xor(sp, 4); sp += __shfl_xor(sp, 8);
        sy += __shfl_xor(sy, 1); sy += __shfl_xor(sy, 2);
        sy += __shfl_xor(sy, 4); sy += __shfl_xor(sy, 8);
        dd += __shfl_xor(dd, 1); dd += __shfl_xor(dd, 2);
        dd += __shfl_xor(dd, 4); dd += __shfl_xor(dd, 8);

        if (q == 0)
            res_acc += sqrtf(sp) - dd / sqrtf(sy);
    }

    // ---- block reduction ----
#pragma unroll
    for (int off = 32; off > 0; off >>= 1)
        res_acc += __shfl_down(res_acc, off, 64);

    const int lane = tid & 63;
    const int wid  = tid >> 6;
    if (lane == 0) wsum[wid] = res_acc;
    __syncthreads();
    if (tid == 0)
        atomicAdd(out, wsum[0] + wsum[1] + wsum[2] + wsum[3]);
}

extern "C" void kernel_launch(void* const* d_in, const int* in_sizes, int n_in,
                              void* d_out, int out_size, void* d_ws, size_t ws_size,
                              hipStream_t stream) {
    const float* input  = (const float*)d_in[0];
    const int*   target = (const int*)d_in[1];   // harness passes integers as int32
    const float* s      = (const float*)d_in[2];
    const float* C      = (const float*)d_in[3];
    // d_in[4] (instance_weights) is unused by the reference.

    float* out = (float*)d_out;
    int N = in_sizes[1];

    // harness poisons d_out and does not re-zero between replays
    hipMemsetAsync(out, 0, sizeof(float) * out_size, stream);

    // 2048 blocks * 16 groups = 32768 rows/sweep -> exactly 8 sweeps at N=262144
    rnorm_kernel<<<2048, BLOCK, 0, stream>>>(input, target, s, C, out, N);
}

// Round 12
// 49.882 us; speedup vs baseline: 1.1977x; 1.0781x over previous
//
#include <hip/hip_runtime.h>
#include <hip/hip_bf16.h>

#define NCLS 13
#define NBUF 3                 // wave-private triple buffer, 2-deep prefetch
#define RPT 4                  // rows per wave-tile
#define TPW 16                 // tiles per wave  -> 64 rows per wave
#define BLOCK 256              // 4 waves -> 256 rows per block
#define CWT (RPT * NCLS * NCLS)   // 676 floats C per wave-tile
#define XWT (RPT * NCLS)          // 52 floats x (or s) per wave-tile

// async global->LDS DMA, 16B/lane; HW writes LDS at uniform base + lane*16
__device__ __forceinline__ void async_cp16(const float* g, float* l) {
    __builtin_amdgcn_global_load_lds(
        (__attribute__((address_space(1))) void*)(const_cast<float*>(g)),
        (__attribute__((address_space(3))) void*)(l),
        16, 0, 0);
}

__global__ __launch_bounds__(BLOCK) void rnorm_kernel(
    const float* __restrict__ input,
    const int* __restrict__ target,
    const float* __restrict__ s,
    const float* __restrict__ C,
    float* __restrict__ out)
{
    // wave-private buffers: 4 waves * 3 bufs * (2704+208+208) B = 37440 B -> 4 blocks/CU
    __shared__ __align__(16) float cbuf[4][NBUF][CWT];
    __shared__ __align__(16) float xbuf[4][NBUF][XWT];
    __shared__ __align__(16) float sbuf[4][NBUF][XWT];
    __shared__ float wsum[4];

    const int tid  = threadIdx.x;
    const int w    = tid >> 6;     // wave 0..3
    const int lane = tid & 63;
    const int rloc = lane >> 4;    // 0..3: row within wave-tile
    const int q    = lane & 15;    // 16 lanes per row, 13 active

    const int w0 = blockIdx.x * (BLOCK) + w * (RPT * TPW);  // wave's first row (64 rows/wave)

    // preload this wave's 64 targets, one per lane; pin so its vmcnt wait
    // happens HERE and never pollutes the counted DMA stream below.
    int trg = target[w0 + lane];
    asm volatile("" : "+v"(trg));

    // exactly 5 DMA instructions per wave-tile (per-wave vmcnt accounting)
    auto stage = [&](int t_idx, int buf) {
        const int r0 = w0 + t_idx * RPT;
        const float4* Cg = (const float4*)(C + (size_t)r0 * (NCLS * NCLS));
        float* cd = &cbuf[w][buf][0];
        async_cp16((const float*)(Cg + lane),       cd + (size_t)lane * 4);
        async_cp16((const float*)(Cg + 64 + lane),  cd + (size_t)(64 + lane) * 4);
        if (lane < CWT / 4 - 128)   // 169 f4 = 64 + 64 + 41
            async_cp16((const float*)(Cg + 128 + lane), cd + (size_t)(128 + lane) * 4);
        const float4* xg = (const float4*)(input + (size_t)r0 * NCLS);
        if (lane < XWT / 4)
            async_cp16((const float*)(xg + lane), &xbuf[w][buf][0] + (size_t)lane * 4);
        const float4* sg = (const float4*)(s + (size_t)r0 * NCLS);
        if (lane < XWT / 4)
            async_cp16((const float*)(sg + lane), &sbuf[w][buf][0] + (size_t)lane * 4);
    };

    float res_acc = 0.0f;

    // prologue: 2-deep prefetch
    stage(0, 0);
    stage(1, 1);
    asm volatile("s_waitcnt vmcnt(5)" ::: "memory");   // tile 0 landed, tile 1 in flight
    __builtin_amdgcn_sched_barrier(0);

    for (int t = 0; t < TPW; ++t) {
        const int bcur = t % NBUF;
        if (t + 2 < TPW)
            stage(t + 2, (t + 2) % NBUF);

        // ---- compute tile t from wave-private LDS ----
        const float* cbt = cbuf[w][bcur];
        const float* xbt = xbuf[w][bcur];
        const float* sbt = sbuf[w][bcur];
        const int tt = __shfl(trg, t * RPT + rloc);   // target of this lane's row

        float sp = 0.0f, sy = 0.0f, dd = 0.0f;
        if (q < NCLS) {
            const float* crow = cbt + rloc * (NCLS * NCLS) + q * NCLS;
            const float* xrow = xbt + rloc * NCLS;
            float zye = 0.0f;
#pragma unroll
            for (int j = 0; j < NCLS; ++j)
                zye = fmaf(crow[j], xrow[j], zye);
            const float zpe = crow[tt];               // one-hot column
            const float svi = sbt[rloc * NCLS + q];
            const float zp = svi - zpe, zy = svi - zye;
            sp = zp * zp; sy = zy * zy; dd = zy * zp;
        }

        sp += __shfl_xor(sp, 1); sp += __shfl_xor(sp, 2);
        sp += __shfl_xor(sp, 4); sp += __shfl_xor(sp, 8);
        sy += __shfl_xor(sy, 1); sy += __shfl_xor(sy, 2);
        sy += __shfl_xor(sy, 4); sy += __shfl_xor(sy, 8);
        dd += __shfl_xor(dd, 1); dd += __shfl_xor(dd, 2);
        dd += __shfl_xor(dd, 4); dd += __shfl_xor(dd, 8);

        if (q == 0)
            res_acc += sqrtf(sp) - dd / sqrtf(sy);

        // counted wait: tile t+1 landed; tile t+2 stays in flight. NO barrier.
        if (t + 1 < TPW) {
            if (t + 2 < TPW) asm volatile("s_waitcnt vmcnt(5)" ::: "memory");
            else             asm volatile("s_waitcnt vmcnt(0)" ::: "memory");
            __builtin_amdgcn_sched_barrier(0);
        }
    }

    // ---- block reduction ----
#pragma unroll
    for (int off = 32; off > 0; off >>= 1)
        res_acc += __shfl_down(res_acc, off, 64);

    if (lane == 0) wsum[w] = res_acc;
    __syncthreads();
    if (tid == 0)
        atomicAdd(out, wsum[0] + wsum[1] + wsum[2] + wsum[3]);
}

extern "C" void kernel_launch(void* const* d_in, const int* in_sizes, int n_in,
                              void* d_out, int out_size, void* d_ws, size_t ws_size,
                              hipStream_t stream) {
    const float* input  = (const float*)d_in[0];
    const int*   target = (const int*)d_in[1];   // harness passes integers as int32
    const float* s      = (const float*)d_in[2];
    const float* C      = (const float*)d_in[3];
    // d_in[4] (instance_weights) is unused by the reference.

    float* out = (float*)d_out;
    int N = in_sizes[1];                          // 262144

    // harness poisons d_out and does not re-zero between replays
    hipMemsetAsync(out, 0, sizeof(float) * out_size, stream);

    const int grid = N / BLOCK;                   // 1024 blocks, 256 rows each, exact
    rnorm_kernel<<<grid, BLOCK, 0, stream>>>(input, target, s, C, out);
}